// Round 1
// baseline (20.433 us; speedup 1.0000x reference)
//
#include <hip/hip_runtime.h>

typedef short short8 __attribute__((ext_vector_type(8)));
typedef float f32x4 __attribute__((ext_vector_type(4)));

static __device__ __forceinline__ unsigned short f2bf(float f) {
    unsigned u = __builtin_bit_cast(unsigned, f);
    u += 0x7FFFu + ((u >> 16) & 1u);   // RNE (values are normal, no NaN handling needed)
    return (unsigned short)(u >> 16);
}

// ws layout: [0, 128KB)  inj  fp32 [8][16][256]
//            [128KB, 256KB) Bt bf16 [256 n][256 k]  (Wp transposed)
#define WS_INJ_BYTES (8 * 16 * 256 * 4)

// Kernel 1: blocks 0..127 -> inj[b][n][:] (n=15 is mean-embedding row)
//           blocks 128..143 -> 64x64 transpose tiles of Wp -> bf16 Bt[n][k]
__global__ __launch_bounds__(256)
void prep_kernel(const float* __restrict__ embs,
                 const float* __restrict__ Wp,
                 const float* __restrict__ We,
                 float* __restrict__ ws_inj,
                 unsigned short* __restrict__ Btg) {
    __shared__ float sh[64 * 65];
    const int bid = blockIdx.x, t = threadIdx.x;
    if (bid < 128) {
        const int b = bid >> 4, n = bid & 15;
        float e;
        if (n == 15) {
            float s = 0.f;
            #pragma unroll
            for (int j = 0; j < 15; ++j) s += embs[(b * 15 + j) * 256 + t];
            e = s * (1.0f / 15.0f);
        } else {
            e = embs[(b * 15 + n) * 256 + t];
        }
        sh[t] = e;
        __syncthreads();
        float acc = 0.f;
        #pragma unroll 4
        for (int k0 = 0; k0 < 256; k0 += 4) {
            float4 e4 = *reinterpret_cast<const float4*>(&sh[k0]);
            acc += e4.x * We[(k0 + 0) * 256 + t];
            acc += e4.y * We[(k0 + 1) * 256 + t];
            acc += e4.z * We[(k0 + 2) * 256 + t];
            acc += e4.w * We[(k0 + 3) * 256 + t];
        }
        ws_inj[(b * 16 + n) * 256 + t] = acc;
    } else {
        const int tt = bid - 128;
        const int kt = (tt >> 2) * 64, n0 = (tt & 3) * 64;
        #pragma unroll
        for (int it = 0; it < 16; ++it) {
            int u = t + it * 256;
            int kl = u >> 6, nl = u & 63;
            sh[kl * 65 + nl] = Wp[(kt + kl) * 256 + n0 + nl];
        }
        __syncthreads();
        #pragma unroll
        for (int it = 0; it < 4; ++it) {
            int v = t + it * 256;
            int nl = v >> 4, kg = v & 15;
            ushort4 o;
            o.x = f2bf(sh[(kg * 4 + 0) * 65 + nl]);
            o.y = f2bf(sh[(kg * 4 + 1) * 65 + nl]);
            o.z = f2bf(sh[(kg * 4 + 2) * 65 + nl]);
            o.w = f2bf(sh[(kg * 4 + 3) * 65 + nl]);
            *reinterpret_cast<ushort4*>(&Btg[(n0 + nl) * 256 + kt + kg * 4]) = o;
        }
    }
}

// Kernel 2: one block = (batch b, 32-pixel tile). 4 waves, each wave owns 64
// output columns. MFMA 16x16x32 bf16, fp32 accumulate, masked-inj epilogue.
__global__ __launch_bounds__(256)
void fused_kernel(const float* __restrict__ patches,
                  const int* __restrict__ locations,
                  const unsigned short* __restrict__ Btg,
                  const float* __restrict__ ws_inj,
                  float* __restrict__ out) {
    __shared__ unsigned short Ash[32 * 256];      // 16 KB, swizzled
    __shared__ unsigned short Bsh[2][256 * 32];   // 2 x 16 KB, swizzled
    __shared__ float injL[16 * 256];              // 16 KB
    __shared__ unsigned maskL[32];
    __shared__ float rcntL[32];

    const int bid = blockIdx.x, t = threadIdx.x;
    const int b = bid >> 5, tile = bid & 31;
    const int p0 = tile * 32;

    // --- A staging: patches[b, p0..p0+32, :] -> bf16 LDS, XOR-swizzled rows
    const float* pbase = patches + (size_t)(b * 1024 + p0) * 256;
    #pragma unroll
    for (int it = 0; it < 8; ++it) {
        int u = t + it * 256;
        int row = u >> 6, c4 = u & 63;
        float4 f = *reinterpret_cast<const float4*>(pbase + row * 256 + c4 * 4);
        ushort4 o;
        o.x = f2bf(f.x); o.y = f2bf(f.y); o.z = f2bf(f.z); o.w = f2bf(f.w);
        int byte = row * 512 + ((c4 * 8) ^ ((row & 7) << 4));
        *reinterpret_cast<ushort4*>(reinterpret_cast<char*>(Ash) + byte) = o;
    }
    // --- inj staging (fp32)
    {
        const float4* src = reinterpret_cast<const float4*>(ws_inj + b * 16 * 256);
        #pragma unroll
        for (int it = 0; it < 4; ++it) {
            int u = t + it * 256;
            reinterpret_cast<float4*>(injL)[u] = src[u];
        }
    }
    // --- per-pixel mask bits + 1/count
    if (t < 32) {
        int p = p0 + t;
        int h = p >> 5, w = p & 31;
        const int* loc = locations + b * 15 * 4;
        unsigned m = 1u << 15;  // full-image box always contains
        #pragma unroll
        for (int nb = 0; nb < 15; ++nb) {
            int y0 = loc[nb * 4 + 0] & ~1;
            int x0 = loc[nb * 4 + 1] & ~1;
            int y1 = (loc[nb * 4 + 2] & ~1) + 2;
            int x1 = (loc[nb * 4 + 3] & ~1) + 2;
            if (h >= y0 && h < y1 && w >= x0 && w < x1) m |= 1u << nb;
        }
        maskL[t] = m;
        rcntL[t] = 1.0f / (float)__popc(m);
    }
    // --- B k-tile 0 staging (Bt[n][0..32), swizzled)
    #pragma unroll
    for (int it = 0; it < 4; ++it) {
        int u = t + it * 256;
        int n = u >> 2, s = u & 3;
        uint4 v = *reinterpret_cast<const uint4*>(Btg + n * 256 + s * 8);
        int byte = n * 64 + ((s * 16) ^ (((n >> 1) & 3) << 4));
        *reinterpret_cast<uint4*>(reinterpret_cast<char*>(&Bsh[0][0]) + byte) = v;
    }
    __syncthreads();

    const int wv = t >> 6, lane = t & 63, lhi = lane >> 4, llo = lane & 15;

    f32x4 acc[2][4];
    #pragma unroll
    for (int mt = 0; mt < 2; ++mt)
        #pragma unroll
        for (int nt = 0; nt < 4; ++nt) acc[mt][nt] = (f32x4){0.f, 0.f, 0.f, 0.f};

    for (int ks = 0; ks < 8; ++ks) {
        const int cur = ks & 1;
        uint4 stg[4];
        int sb[4];
        const bool pref = (ks < 7);
        if (pref) {  // issue next k-tile's global loads early (hide under MFMA)
            int kk = (ks + 1) * 32;
            #pragma unroll
            for (int it = 0; it < 4; ++it) {
                int u = t + it * 256;
                int n = u >> 2, s = u & 3;
                stg[it] = *reinterpret_cast<const uint4*>(Btg + n * 256 + kk + s * 8);
                sb[it] = n * 64 + ((s * 16) ^ (((n >> 1) & 3) << 4));
            }
        }
        const int k0 = ks * 32;
        short8 af[2], bfr[4];
        #pragma unroll
        for (int mt = 0; mt < 2; ++mt) {
            int row = mt * 16 + llo;
            int byte = row * 512 + (((k0 + lhi * 8) * 2) ^ ((row & 7) << 4));
            af[mt] = *reinterpret_cast<const short8*>(reinterpret_cast<const char*>(Ash) + byte);
        }
        #pragma unroll
        for (int nt = 0; nt < 4; ++nt) {
            int nrow = wv * 64 + nt * 16 + llo;
            int byte = nrow * 64 + ((lhi * 16) ^ (((nrow >> 1) & 3) << 4));
            bfr[nt] = *reinterpret_cast<const short8*>(reinterpret_cast<const char*>(&Bsh[cur][0]) + byte);
        }
        #pragma unroll
        for (int mt = 0; mt < 2; ++mt)
            #pragma unroll
            for (int nt = 0; nt < 4; ++nt)
                acc[mt][nt] = __builtin_amdgcn_mfma_f32_16x16x32_bf16(af[mt], bfr[nt], acc[mt][nt], 0, 0, 0);
        if (pref) {
            #pragma unroll
            for (int it = 0; it < 4; ++it)
                *reinterpret_cast<uint4*>(reinterpret_cast<char*>(&Bsh[cur ^ 1][0]) + sb[it]) = stg[it];
        }
        __syncthreads();
    }

    // --- epilogue: out = proj + (1/cnt) * sum_masked inj
    unsigned mv[8];
    float rc[8];
    #pragma unroll
    for (int mt = 0; mt < 2; ++mt)
        #pragma unroll
        for (int j = 0; j < 4; ++j) {
            int pix = mt * 16 + lhi * 4 + j;
            mv[mt * 4 + j] = maskL[pix];
            rc[mt * 4 + j] = rcntL[pix];
        }
    #pragma unroll
    for (int n = 0; n < 16; ++n) {
        float iv[4];
        #pragma unroll
        for (int nt = 0; nt < 4; ++nt) iv[nt] = injL[n * 256 + wv * 64 + nt * 16 + llo];
        #pragma unroll
        for (int mt = 0; mt < 2; ++mt)
            #pragma unroll
            for (int j = 0; j < 4; ++j) {
                float f = ((mv[mt * 4 + j] >> n) & 1u) ? rc[mt * 4 + j] : 0.0f;
                #pragma unroll
                for (int nt = 0; nt < 4; ++nt) acc[mt][nt][j] += f * iv[nt];
            }
    }
    float* ob = out + (size_t)(b * 1024 + p0) * 256;
    #pragma unroll
    for (int mt = 0; mt < 2; ++mt)
        #pragma unroll
        for (int nt = 0; nt < 4; ++nt)
            #pragma unroll
            for (int j = 0; j < 4; ++j)
                ob[(mt * 16 + lhi * 4 + j) * 256 + wv * 64 + nt * 16 + llo] = acc[mt][nt][j];
}

extern "C" void kernel_launch(void* const* d_in, const int* in_sizes, int n_in,
                              void* d_out, int out_size, void* d_ws, size_t ws_size,
                              hipStream_t stream) {
    const float* patches = (const float*)d_in[0];
    const float* embs    = (const float*)d_in[1];
    const int*   locs    = (const int*)d_in[2];
    const float* Wp      = (const float*)d_in[3];
    const float* We      = (const float*)d_in[4];
    float* out = (float*)d_out;

    float* ws_inj = (float*)d_ws;
    unsigned short* Btg = (unsigned short*)((char*)d_ws + WS_INJ_BYTES);

    prep_kernel<<<144, 256, 0, stream>>>(embs, Wp, We, ws_inj, Btg);
    fused_kernel<<<256, 256, 0, stream>>>(patches, locs, Btg, ws_inj, out);
}